// Round 1
// baseline (337.748 us; speedup 1.0000x reference)
//
#include <hip/hip_runtime.h>

using uint = unsigned int;
using ushort = unsigned short;

typedef float f32x4 __attribute__((ext_vector_type(4)));
using short8 = __attribute__((ext_vector_type(8))) short;

// round-to-nearest-even f32 -> bf16 (as ushort), values are finite here
__device__ __forceinline__ ushort f2bf(float f) {
  uint u = __float_as_uint(f);
  u += 0x7fffu + ((u >> 16) & 1u);
  return (ushort)(u >> 16);
}

// async global->LDS, 16B per lane. LDS dest is wave-uniform base + lane*16
// (we pass per-lane ptr = base + lane*16 which matches HW semantics).
#define GLOAD_LDS16(gptr, lptr)                                                   \
  __builtin_amdgcn_global_load_lds(                                               \
      (const __attribute__((address_space(1))) void*)(gptr),                      \
      (__attribute__((address_space(3))) void*)(lptr), 16, 0, 0)

// ---------------------------------------------------------------- cast kernel
__global__ void cast_f32_to_bf16(const float* __restrict__ in,
                                 ushort* __restrict__ out, int n4) {
  int stride = gridDim.x * blockDim.x;
  for (int i = blockIdx.x * blockDim.x + threadIdx.x; i < n4; i += stride) {
    float4 v = reinterpret_cast<const float4*>(in)[i];
    ushort4 o;
    o.x = f2bf(v.x); o.y = f2bf(v.y); o.z = f2bf(v.z); o.w = f2bf(v.w);
    reinterpret_cast<ushort4*>(out)[i] = o;
  }
}

// ------------------------------------------------- 128x128 BK=32 GEMM mainloop
// C[m,n] = sum_k A[m,k] * W[n,k]; A,W bf16 row-major, K-contiguous.
// m97 structure: 2 barriers/K-step, global_load_lds width 16, 4 waves 2x2.
__device__ __forceinline__ void gemm128_mainloop(const ushort* __restrict__ A,
                                                 const ushort* __restrict__ W,
                                                 int K, ushort* As, ushort* Bs,
                                                 f32x4 (&acc)[4][4]) {
  const int tid = threadIdx.x;
  const int lane = tid & 63;
  const int wr = (tid >> 7) & 1;  // wave row
  const int wc = (tid >> 6) & 1;  // wave col
  const char* aP = (const char*)(A + (size_t)(tid >> 2) * K) + (tid & 3) * 16;
  const char* bP = (const char*)(W + (size_t)(tid >> 2) * K) + (tid & 3) * 16;
  const size_t rowHop = (size_t)64 * K * 2;  // +64 rows, bytes
  ushort* aL0 = As + tid * 8;         // byte off tid*16
  ushort* aL1 = As + 2048 + tid * 8;  // rows 64..127
  ushort* bL0 = Bs + tid * 8;
  ushort* bL1 = Bs + 2048 + tid * 8;
  const int ar = lane & 15;        // fragment row
  const int ak = (lane >> 4) * 8;  // fragment k-elem

  for (int k0 = 0; k0 < K; k0 += 32) {
    GLOAD_LDS16(aP, aL0);
    GLOAD_LDS16(aP + rowHop, aL1);
    GLOAD_LDS16(bP, bL0);
    GLOAD_LDS16(bP + rowHop, bL1);
    aP += 64; bP += 64;  // 32 bf16 = 64 bytes
    __syncthreads();     // drains vmcnt -> LDS ready
    short8 af[4], bf[4];
#pragma unroll
    for (int i = 0; i < 4; ++i)
      af[i] = *reinterpret_cast<const short8*>(&As[(wr * 64 + i * 16 + ar) * 32 + ak]);
#pragma unroll
    for (int i = 0; i < 4; ++i)
      bf[i] = *reinterpret_cast<const short8*>(&Bs[(wc * 64 + i * 16 + ar) * 32 + ak]);
#pragma unroll
    for (int mi = 0; mi < 4; ++mi)
#pragma unroll
      for (int ni = 0; ni < 4; ++ni)
        acc[mi][ni] = __builtin_amdgcn_mfma_f32_16x16x32_bf16(af[mi], bf[ni],
                                                              acc[mi][ni], 0, 0, 0);
    __syncthreads();
  }
}

// -------------------------------------------------------------- fused QKV GEMM
// grid.x: [0,16) -> Q (N=2048), [16,20) -> K (N=512), [20,24) -> V (N=512, out
// transposed to Vt[B][512][S] so attention PV reads are kv-contiguous).
__global__ __launch_bounds__(256) void qkv_gemm(
    const ushort* __restrict__ Xb, const ushort* __restrict__ Wq,
    const ushort* __restrict__ Wk, const ushort* __restrict__ Wv,
    const float* __restrict__ bq, const float* __restrict__ bk,
    const float* __restrict__ bv, ushort* __restrict__ Qb,
    ushort* __restrict__ Kb, ushort* __restrict__ Vt) {
  __shared__ ushort As[128 * 32], Bs[128 * 32];
  const int bx = blockIdx.x, by = blockIdx.y;
  const ushort* W; const float* bias; ushort* out;
  int n0, mode, ldo;
  if (bx < 16)      { W = Wq; bias = bq; out = Qb; n0 = bx * 128;        mode = 0; ldo = 2048; }
  else if (bx < 20) { W = Wk; bias = bk; out = Kb; n0 = (bx - 16) * 128; mode = 0; ldo = 512; }
  else              { W = Wv; bias = bv; out = Vt; n0 = (bx - 20) * 128; mode = 1; ldo = 0; }

  f32x4 acc[4][4] = {};
  gemm128_mainloop(Xb + (size_t)by * 128 * 2048, W + (size_t)n0 * 2048, 2048, As, Bs, acc);

  const int lane = threadIdx.x & 63;
  const int wr = (threadIdx.x >> 7) & 1, wc = (threadIdx.x >> 6) & 1;
  const int r0 = by * 128 + wr * 64 + ((lane >> 4) * 4);
  const int c0 = wc * 64 + (lane & 15);
#pragma unroll
  for (int mi = 0; mi < 4; ++mi)
#pragma unroll
    for (int ni = 0; ni < 4; ++ni) {
      const int col = c0 + ni * 16;  // local col within 128-tile
      const float bb = bias[n0 + col];
#pragma unroll
      for (int j = 0; j < 4; ++j) {
        const int row = r0 + mi * 16 + j;
        const float v = acc[mi][ni][j] + bb;
        if (mode == 0) {
          out[(size_t)row * ldo + n0 + col] = f2bf(v);
        } else {  // V transposed: Vt[(b*512 + n)*2048 + s]
          const int b = row >> 11, s = row & 2047;
          out[((size_t)(b * 512 + n0 + col) << 11) + s] = f2bf(v);
        }
      }
    }
}

// ------------------------------------------------------------ out-projection
__global__ __launch_bounds__(256) void out_gemm(const ushort* __restrict__ Mid,
                                                const ushort* __restrict__ Wo,
                                                const float* __restrict__ bo,
                                                float* __restrict__ Out) {
  __shared__ ushort As[128 * 32], Bs[128 * 32];
  const int bx = blockIdx.x, by = blockIdx.y;
  f32x4 acc[4][4] = {};
  gemm128_mainloop(Mid + (size_t)by * 128 * 2048, Wo + (size_t)bx * 128 * 2048,
                   2048, As, Bs, acc);
  const int lane = threadIdx.x & 63;
  const int wr = (threadIdx.x >> 7) & 1, wc = (threadIdx.x >> 6) & 1;
  const int r0 = by * 128 + wr * 64 + ((lane >> 4) * 4);
  const int c0 = bx * 128 + wc * 64 + (lane & 15);
#pragma unroll
  for (int mi = 0; mi < 4; ++mi)
#pragma unroll
    for (int ni = 0; ni < 4; ++ni) {
      const int col = c0 + ni * 16;
      const float bb = bo[col];
#pragma unroll
      for (int j = 0; j < 4; ++j)
        Out[(size_t)(r0 + mi * 16 + j) * 2048 + col] = acc[mi][ni][j] + bb;
    }
}

// ------------------------------------------------------------ flash attention
// grid (S/64, H, B); 4 waves, each owns 16 q-rows. KVBLK=64.
// K LDS [64][128] bf16, Vt LDS [128][64] (d-major), both XOR-swizzled
// (byte ^= (row&7)<<4) via linear-dest global_load_lds + pre-swizzled source.
__global__ __launch_bounds__(256) void attn_fwd(const ushort* __restrict__ Q,
                                                const ushort* __restrict__ Kb,
                                                const ushort* __restrict__ Vt,
                                                ushort* __restrict__ Mid) {
  __shared__ ushort Ks[64 * 128];
  __shared__ ushort Vs[128 * 64];
  __shared__ ushort Ps[4][16][72];  // per-wave P (16 q x 64 kv), +8 col pad

  const int tid = threadIdx.x, lane = tid & 63, wave = tid >> 6;
  const int h = blockIdx.y, b = blockIdx.z, g = h >> 2;
  const int q0 = blockIdx.x * 64 + wave * 16;
  const int lr = lane & 15, lg = lane >> 4;

  // Q strip (16 rows x 128) into regs as A-fragments
  short8 aq[4];
  {
    const ushort* qp = Q + (size_t)(b * 2048 + q0 + lr) * 2048 + h * 128 + lg * 8;
#pragma unroll
    for (int kk = 0; kk < 4; ++kk)
      aq[kk] = *reinterpret_cast<const short8*>(qp + kk * 32);
  }

  const char* kbase = (const char*)Kb + ((size_t)b * 2048 * 512 + g * 128) * 2;
  const char* vbase = (const char*)Vt + ((size_t)(b * 512 + g * 128) * 2048) * 2;
  int kRow[4], kOff[4], vRow[4], vOff[4];
#pragma unroll
  for (int i = 0; i < 4; ++i) {
    const int off = (i * 256 + tid) * 16;
    const int r = off >> 8, c = off & 255;       // K tile: 256B rows
    kRow[i] = r; kOff[i] = c ^ ((r & 7) << 4);
    const int rv = off >> 7, cv = off & 127;     // V tile: 128B rows
    vRow[i] = rv; vOff[i] = cv ^ ((rv & 7) << 4);
  }

  float m[4], l[4];
  f32x4 o[8] = {};
#pragma unroll
  for (int j = 0; j < 4; ++j) { m[j] = -3.0e38f; l[j] = 0.f; }

  const float sc = 0.08838834764831843f * 1.44269504088896340736f;  // 1/sqrt(128)*log2e

  for (int t = 0; t < 32; ++t) {
    const int kv0 = t * 64;
#pragma unroll
    for (int i = 0; i < 4; ++i) {
      GLOAD_LDS16(kbase + (size_t)(kv0 + kRow[i]) * 1024 + kOff[i],
                  (char*)Ks + (i * 256 + tid) * 16);
      GLOAD_LDS16(vbase + (size_t)vRow[i] * 4096 + kv0 * 2 + vOff[i],
                  (char*)Vs + (i * 256 + tid) * 16);
    }
    __syncthreads();

    // S = Q K^T  (per wave: 16 x 64)
    f32x4 s[4];
#pragma unroll
    for (int nf = 0; nf < 4; ++nf) {
      f32x4 a = {0.f, 0.f, 0.f, 0.f};
      const int row = nf * 16 + lr;
      const int sw = (row & 7) << 4;
#pragma unroll
      for (int kk = 0; kk < 4; ++kk) {
        short8 bk = *reinterpret_cast<const short8*>(
            (const char*)Ks + row * 256 + ((kk * 64 + lg * 16) ^ sw));
        a = __builtin_amdgcn_mfma_f32_16x16x32_bf16(aq[kk], bk, a, 0, 0, 0);
      }
      s[nf] = a;
    }

    // online softmax; row r = lg*4+j lives in 16-lane group lg, register j
    float alpha[4];
#pragma unroll
    for (int j = 0; j < 4; ++j) {
      float mx = fmaxf(fmaxf(s[0][j], s[1][j]), fmaxf(s[2][j], s[3][j])) * sc;
#pragma unroll
      for (int d = 1; d < 16; d <<= 1) mx = fmaxf(mx, __shfl_xor(mx, d, 64));
      const float mn = fmaxf(m[j], mx);
      alpha[j] = exp2f(m[j] - mn);
      m[j] = mn;
      float rs = 0.f;
#pragma unroll
      for (int nf = 0; nf < 4; ++nf) {
        const float p = exp2f(s[nf][j] * sc - mn);
        rs += p;
        Ps[wave][lg * 4 + j][nf * 16 + lr] = f2bf(p);
      }
#pragma unroll
      for (int d = 1; d < 16; d <<= 1) rs += __shfl_xor(rs, d, 64);
      l[j] = l[j] * alpha[j] + rs;
    }
#pragma unroll
    for (int df = 0; df < 8; ++df)
#pragma unroll
      for (int j = 0; j < 4; ++j) o[df][j] *= alpha[j];

    // O += P V   (P from per-wave LDS, V from swizzled d-major tile)
#pragma unroll
    for (int kk = 0; kk < 2; ++kk) {
      short8 ap = *reinterpret_cast<const short8*>(&Ps[wave][lr][kk * 32 + lg * 8]);
#pragma unroll
      for (int df = 0; df < 8; ++df) {
        const int rv = df * 16 + lr;
        const int sw = (rv & 7) << 4;
        short8 bv = *reinterpret_cast<const short8*>(
            (const char*)Vs + rv * 128 + ((kk * 64 + lg * 16) ^ sw));
        o[df] = __builtin_amdgcn_mfma_f32_16x16x32_bf16(ap, bv, o[df], 0, 0, 0);
      }
    }
    __syncthreads();
  }

  // epilogue: Mid[b*S+q][h*128+d] = O / l
  ushort* mp = Mid + (size_t)(b * 2048 + q0 + lg * 4) * 2048 + h * 128;
#pragma unroll
  for (int j = 0; j < 4; ++j) {
    const float inv = 1.f / l[j];
#pragma unroll
    for (int df = 0; df < 8; ++df)
      mp[(size_t)j * 2048 + df * 16 + lr] = f2bf(o[df][j] * inv);
  }
}

// ------------------------------------------------------------------- launcher
extern "C" void kernel_launch(void* const* d_in, const int* in_sizes, int n_in,
                              void* d_out, int out_size, void* d_ws, size_t ws_size,
                              hipStream_t stream) {
  const float* X  = (const float*)d_in[0];
  const float* Wq = (const float*)d_in[1];
  const float* bq = (const float*)d_in[2];
  const float* Wk = (const float*)d_in[3];
  const float* bk = (const float*)d_in[4];
  const float* Wv = (const float*)d_in[5];
  const float* bv = (const float*)d_in[6];
  const float* Wo = (const float*)d_in[7];
  const float* bo = (const float*)d_in[8];
  float* Out = (float*)d_out;

  char* ws = (char*)d_ws;
  ushort* Xb   = (ushort*)(ws);              // 16 MB  [B*S,2048]
  ushort* Wqb  = (ushort*)(ws + 16777216);   //  8 MB
  ushort* Wkb  = (ushort*)(ws + 25165824);   //  2 MB
  ushort* Wvb  = (ushort*)(ws + 27262976);   //  2 MB
  ushort* Wob  = (ushort*)(ws + 29360128);   //  8 MB
  ushort* Qb   = (ushort*)(ws + 37748736);   // 16 MB  [B*S,2048]
  ushort* Kbuf = (ushort*)(ws + 54525952);   //  4 MB  [B*S,512]
  ushort* Vtb  = (ushort*)(ws + 58720256);   //  4 MB  [B,512,S] (transposed)
  ushort* Midb = (ushort*)(ws + 62914560);   // 16 MB  [B*S,2048]

  auto cast = [&](const float* src, ushort* dst, int n) {
    int n4 = n >> 2;
    int blocks = (n4 + 255) >> 8;
    if (blocks > 2048) blocks = 2048;
    cast_f32_to_bf16<<<dim3(blocks), dim3(256), 0, stream>>>(src, dst, n4);
  };
  cast(X,  Xb,  8388608);
  cast(Wq, Wqb, 4194304);
  cast(Wk, Wkb, 1048576);
  cast(Wv, Wvb, 1048576);
  cast(Wo, Wob, 4194304);

  qkv_gemm<<<dim3(24, 32), 256, 0, stream>>>(Xb, Wqb, Wkb, Wvb, bq, bk, bv,
                                             Qb, Kbuf, Vtb);
  attn_fwd<<<dim3(32, 16, 2), 256, 0, stream>>>(Qb, Kbuf, Vtb, Midb);
  out_gemm<<<dim3(16, 32), 256, 0, stream>>>(Midb, Wob, bo, Out);
}

// Round 2
// 227.922 us; speedup vs baseline: 1.4819x; 1.4819x over previous
//
#include <hip/hip_runtime.h>

using uint = unsigned int;
using ushort = unsigned short;

typedef float f32x4 __attribute__((ext_vector_type(4)));
typedef float f32x16 __attribute__((ext_vector_type(16)));
typedef uint u32x4 __attribute__((ext_vector_type(4)));
using short8 = __attribute__((ext_vector_type(8))) short;

// round-to-nearest-even f32 -> bf16 (as ushort), values are finite here
__device__ __forceinline__ ushort f2bf(float f) {
  uint u = __float_as_uint(f);
  u += 0x7fffu + ((u >> 16) & 1u);
  return (ushort)(u >> 16);
}

// async global->LDS, 16B per lane. LDS dest is wave-uniform base + lane*16
#define GLOAD_LDS16(gptr, lptr)                                                   \
  __builtin_amdgcn_global_load_lds(                                               \
      (const __attribute__((address_space(1))) void*)(gptr),                      \
      (__attribute__((address_space(3))) void*)(lptr), 16, 0, 0)

// ---------------------------------------------------------------- cast kernel
__global__ void cast_f32_to_bf16(const float* __restrict__ in,
                                 ushort* __restrict__ out, int n4) {
  int stride = gridDim.x * blockDim.x;
  for (int i = blockIdx.x * blockDim.x + threadIdx.x; i < n4; i += stride) {
    float4 v = reinterpret_cast<const float4*>(in)[i];
    ushort4 o;
    o.x = f2bf(v.x); o.y = f2bf(v.y); o.z = f2bf(v.z); o.w = f2bf(v.w);
    reinterpret_cast<ushort4*>(out)[i] = o;
  }
}

// ------------------------------------------------- 128x128 BK=32 GEMM mainloop
__device__ __forceinline__ void gemm128_mainloop(const ushort* __restrict__ A,
                                                 const ushort* __restrict__ W,
                                                 int K, ushort* As, ushort* Bs,
                                                 f32x4 (&acc)[4][4]) {
  const int tid = threadIdx.x;
  const int lane = tid & 63;
  const int wr = (tid >> 7) & 1;
  const int wc = (tid >> 6) & 1;
  const char* aP = (const char*)(A + (size_t)(tid >> 2) * K) + (tid & 3) * 16;
  const char* bP = (const char*)(W + (size_t)(tid >> 2) * K) + (tid & 3) * 16;
  const size_t rowHop = (size_t)64 * K * 2;
  ushort* aL0 = As + tid * 8;
  ushort* aL1 = As + 2048 + tid * 8;
  ushort* bL0 = Bs + tid * 8;
  ushort* bL1 = Bs + 2048 + tid * 8;
  const int ar = lane & 15;
  const int ak = (lane >> 4) * 8;

  for (int k0 = 0; k0 < K; k0 += 32) {
    GLOAD_LDS16(aP, aL0);
    GLOAD_LDS16(aP + rowHop, aL1);
    GLOAD_LDS16(bP, bL0);
    GLOAD_LDS16(bP + rowHop, bL1);
    aP += 64; bP += 64;
    __syncthreads();
    short8 af[4], bf[4];
#pragma unroll
    for (int i = 0; i < 4; ++i)
      af[i] = *reinterpret_cast<const short8*>(&As[(wr * 64 + i * 16 + ar) * 32 + ak]);
#pragma unroll
    for (int i = 0; i < 4; ++i)
      bf[i] = *reinterpret_cast<const short8*>(&Bs[(wc * 64 + i * 16 + ar) * 32 + ak]);
#pragma unroll
    for (int mi = 0; mi < 4; ++mi)
#pragma unroll
      for (int ni = 0; ni < 4; ++ni)
        acc[mi][ni] = __builtin_amdgcn_mfma_f32_16x16x32_bf16(af[mi], bf[ni],
                                                              acc[mi][ni], 0, 0, 0);
    __syncthreads();
  }
}

// -------------------------------------------------------------- fused QKV GEMM
__global__ __launch_bounds__(256) void qkv_gemm(
    const ushort* __restrict__ Xb, const ushort* __restrict__ Wq,
    const ushort* __restrict__ Wk, const ushort* __restrict__ Wv,
    const float* __restrict__ bq, const float* __restrict__ bk,
    const float* __restrict__ bv, ushort* __restrict__ Qb,
    ushort* __restrict__ Kb, ushort* __restrict__ Vt) {
  __shared__ ushort As[128 * 32], Bs[128 * 32];
  const int bx = blockIdx.x, by = blockIdx.y;
  const ushort* W; const float* bias; ushort* out;
  int n0, mode, ldo;
  if (bx < 16)      { W = Wq; bias = bq; out = Qb; n0 = bx * 128;        mode = 0; ldo = 2048; }
  else if (bx < 20) { W = Wk; bias = bk; out = Kb; n0 = (bx - 16) * 128; mode = 0; ldo = 512; }
  else              { W = Wv; bias = bv; out = Vt; n0 = (bx - 20) * 128; mode = 1; ldo = 0; }

  f32x4 acc[4][4] = {};
  gemm128_mainloop(Xb + (size_t)by * 128 * 2048, W + (size_t)n0 * 2048, 2048, As, Bs, acc);

  const int lane = threadIdx.x & 63;
  const int wr = (threadIdx.x >> 7) & 1, wc = (threadIdx.x >> 6) & 1;
  const int r0 = by * 128 + wr * 64 + ((lane >> 4) * 4);
  const int c0 = wc * 64 + (lane & 15);
#pragma unroll
  for (int mi = 0; mi < 4; ++mi)
#pragma unroll
    for (int ni = 0; ni < 4; ++ni) {
      const int col = c0 + ni * 16;
      const float bb = bias[n0 + col];
#pragma unroll
      for (int j = 0; j < 4; ++j) {
        const int row = r0 + mi * 16 + j;
        const float v = acc[mi][ni][j] + bb;
        if (mode == 0) {
          out[(size_t)row * ldo + n0 + col] = f2bf(v);
        } else {
          const int b = row >> 11, s = row & 2047;
          out[((size_t)(b * 512 + n0 + col) << 11) + s] = f2bf(v);
        }
      }
    }
}

// ------------------------------------------------------------ out-projection
__global__ __launch_bounds__(256) void out_gemm(const ushort* __restrict__ Mid,
                                                const ushort* __restrict__ Wo,
                                                const float* __restrict__ bo,
                                                float* __restrict__ Out) {
  __shared__ ushort As[128 * 32], Bs[128 * 32];
  const int bx = blockIdx.x, by = blockIdx.y;
  f32x4 acc[4][4] = {};
  gemm128_mainloop(Mid + (size_t)by * 128 * 2048, Wo + (size_t)bx * 128 * 2048,
                   2048, As, Bs, acc);
  const int lane = threadIdx.x & 63;
  const int wr = (threadIdx.x >> 7) & 1, wc = (threadIdx.x >> 6) & 1;
  const int r0 = by * 128 + wr * 64 + ((lane >> 4) * 4);
  const int c0 = bx * 128 + wc * 64 + (lane & 15);
#pragma unroll
  for (int mi = 0; mi < 4; ++mi)
#pragma unroll
    for (int ni = 0; ni < 4; ++ni) {
      const int col = c0 + ni * 16;
      const float bb = bo[col];
#pragma unroll
      for (int j = 0; j < 4; ++j)
        Out[(size_t)(r0 + mi * 16 + j) * 2048 + col] = acc[mi][ni][j] + bb;
    }
}

// ------------------------------------------------------------ flash attention
// Swapped-QK^T 32x32 structure (m214-style). 4 waves x 32 q-rows = 128 q/block.
// grid (S/128, H, B). KVBLK=64, K/V double-buffered in LDS, XOR-swizzled.
// Lane holds P-row for q=lane&31 across 2 f32x16 accs; softmax in-register;
// P->bf16 A-frags via v_cvt_pk_bf16_f32 + permlane32_swap; defer-max THR=8.
__global__ __launch_bounds__(256, 2) void attn_fwd(const ushort* __restrict__ Q,
                                                   const ushort* __restrict__ Kb,
                                                   const ushort* __restrict__ Vt,
                                                   ushort* __restrict__ Mid) {
  __shared__ ushort Ks[2][64 * 128];
  __shared__ ushort Vs[2][128 * 64];

  const int tid = threadIdx.x, lane = tid & 63, wave = tid >> 6;
  const int h = blockIdx.y, b = blockIdx.z, g = h >> 2;
  const int q0w = blockIdx.x * 128 + wave * 32;
  const int lq = lane & 31, hi = lane >> 5;

  // staging address precompute (both-sides swizzle: linear LDS dest,
  // inverse-XOR'd global source, XOR'd read)
  const char* kbase = (const char*)Kb + ((size_t)b * 2048 * 512 + g * 128) * 2;
  const char* vbase = (const char*)Vt + ((size_t)(b * 512 + g * 128) * 2048) * 2;
  int kRow[4], kOff[4], vRow[4], vOff[4];
#pragma unroll
  for (int i = 0; i < 4; ++i) {
    const int off = (i * 256 + tid) * 16;
    const int r = off >> 8, c = off & 255;   // K tile rows: 256B
    kRow[i] = r; kOff[i] = c ^ ((r & 7) << 4);
    const int rv = off >> 7, cv = off & 127; // V tile rows: 128B
    vRow[i] = rv; vOff[i] = cv ^ ((rv & 7) << 4);
  }

  // prologue: stage tile 0 into buf 0
#pragma unroll
  for (int i = 0; i < 4; ++i) {
    GLOAD_LDS16(kbase + (size_t)kRow[i] * 1024 + kOff[i],
                (char*)Ks[0] + (i * 256 + tid) * 16);
    GLOAD_LDS16(vbase + (size_t)vRow[i] * 4096 + vOff[i],
                (char*)Vs[0] + (i * 256 + tid) * 16);
  }

  // Q strip: B-frag per dblk: Q[q0w+lq][dblk*16 + hi*8 + j]
  short8 qf[8];
  {
    const ushort* qp = Q + (size_t)(b * 2048 + q0w + lq) * 2048 + h * 128 + hi * 8;
#pragma unroll
    for (int dblk = 0; dblk < 8; ++dblk)
      qf[dblk] = *reinterpret_cast<const short8*>(qp + dblk * 16);
  }

  float m_s = -3.0e38f, l_s = 0.f;
  f32x16 o[4] = {};
  const float sc2 = 0.08838834764831843f * 1.44269504088896340736f;  // /sqrt(128)*log2e

  __syncthreads();

  for (int t = 0; t < 32; ++t) {
    const int cur = t & 1;
    // prefetch next tile into other buffer (drained by end-of-loop barrier)
    if (t < 31) {
      const int kv0 = (t + 1) * 64;
#pragma unroll
      for (int i = 0; i < 4; ++i) {
        GLOAD_LDS16(kbase + (size_t)(kv0 + kRow[i]) * 1024 + kOff[i],
                    (char*)Ks[cur ^ 1] + (i * 256 + tid) * 16);
        GLOAD_LDS16(vbase + (size_t)vRow[i] * 4096 + kv0 * 2 + vOff[i],
                    (char*)Vs[cur ^ 1] + (i * 256 + tid) * 16);
      }
    }

    // ---- S^T = K Q^T: lane holds S[kv][q=lq], kv spread over regs ----
    const char* ksb = (const char*)Ks[cur];
    f32x16 st0 = {}, st1 = {};
    const int kcol = (32 * 0 + 16 * hi);  // byte col base per dblk added below
    const int ksw = (lq & 7) << 4;
    __builtin_amdgcn_s_setprio(1);
#pragma unroll
    for (int dblk = 0; dblk < 8; ++dblk) {
      const int cb = (dblk * 32 + 16 * hi) ^ ksw;
      short8 kf0 = *reinterpret_cast<const short8*>(ksb + lq * 256 + cb);
      short8 kf1 = *reinterpret_cast<const short8*>(ksb + (32 + lq) * 256 + cb);
      st0 = __builtin_amdgcn_mfma_f32_32x32x16_bf16(kf0, qf[dblk], st0, 0, 0, 0);
      st1 = __builtin_amdgcn_mfma_f32_32x32x16_bf16(kf1, qf[dblk], st1, 0, 0, 0);
    }
    __builtin_amdgcn_s_setprio(0);
    (void)kcol;

    // ---- online softmax, fully in-register for q=lq ----
    float pm = fmaxf(st0[0], st0[1]);
#pragma unroll
    for (int r = 2; r < 16; ++r) pm = fmaxf(pm, st0[r]);
#pragma unroll
    for (int r = 0; r < 16; ++r) pm = fmaxf(pm, st1[r]);
    pm = fmaxf(pm, __shfl_xor(pm, 32, 64));
    const float msc = pm * sc2;

    if (__any(msc > m_s + 8.f)) {  // defer-max: rescale only on real growth
      const float mnew = fmaxf(m_s, msc);
      const float alpha = exp2f(m_s - mnew);
      m_s = mnew;
      l_s *= alpha;
#pragma unroll
      for (int r = 0; r < 16; ++r) {
        const int qr = (r & 3) + 8 * (r >> 2) + 4 * hi;
        const float ar = __shfl(alpha, qr, 64);
#pragma unroll
        for (int dblk = 0; dblk < 4; ++dblk) o[dblk][r] *= ar;
      }
    }

    float rs = 0.f;
#pragma unroll
    for (int r = 0; r < 16; ++r) {
      st0[r] = exp2f(fmaf(st0[r], sc2, -m_s));
      rs += st0[r];
    }
#pragma unroll
    for (int r = 0; r < 16; ++r) {
      st1[r] = exp2f(fmaf(st1[r], sc2, -m_s));
      rs += st1[r];
    }
    rs += __shfl_xor(rs, 32, 64);
    l_s += rs;

    // ---- pack P -> bf16 A-frags: cvt_pk + permlane32_swap ----
    short8 pa[4];
#pragma unroll
    for (int half = 0; half < 2; ++half) {
      const f32x16 pt = half ? st1 : st0;
#pragma unroll
      for (int kk = 0; kk < 2; ++kk) {
        const int Rx = kk * 8;
        uint w0, w1, w2, w3;
#pragma unroll
        for (int s2 = 0; s2 < 2; ++s2) {
          const int s = s2 * 2;
          const float x0 = pt[Rx + s],     x1 = pt[Rx + s + 1];
          const float y0 = pt[Rx + 4 + s], y1 = pt[Rx + 4 + s + 1];
          uint x, y;
          asm("v_cvt_pk_bf16_f32 %0, %1, %2" : "=v"(x) : "v"(x0), "v"(x1));
          asm("v_cvt_pk_bf16_f32 %0, %1, %2" : "=v"(y) : "v"(y0), "v"(y1));
          auto sw = __builtin_amdgcn_permlane32_swap(x, y, false, false);
          if (s2 == 0) { w0 = sw[0]; w2 = sw[1]; }
          else         { w1 = sw[0]; w3 = sw[1]; }
        }
        u32x4 wv = {w0, w1, w2, w3};
        pa[half * 2 + kk] = __builtin_bit_cast(short8, wv);
      }
    }

    // ---- O += P V ----
    const char* vsb = (const char*)Vs[cur];
    __builtin_amdgcn_s_setprio(1);
#pragma unroll
    for (int dblk = 0; dblk < 4; ++dblk) {
      const int rv = dblk * 32 + lq;
      const int vsw = (rv & 7) << 4;
#pragma unroll
      for (int ks = 0; ks < 4; ++ks) {
        short8 vf = *reinterpret_cast<const short8*>(
            vsb + rv * 128 + ((ks * 32 + 16 * hi) ^ vsw));
        o[dblk] = __builtin_amdgcn_mfma_f32_32x32x16_bf16(pa[ks], vf, o[dblk], 0, 0, 0);
      }
    }
    __builtin_amdgcn_s_setprio(0);

    __syncthreads();  // next-tile stage complete + buffer reuse guard
  }

  // ---- epilogue: Mid[b*S + q][h*128 + d] = O / l ----
  const float linv = 1.f / l_s;
#pragma unroll
  for (int r = 0; r < 16; ++r) {
    const int qr = (r & 3) + 8 * (r >> 2) + 4 * hi;
    const float lv = __shfl(linv, qr, 64);
    ushort* mp = Mid + (size_t)(b * 2048 + q0w + qr) * 2048 + h * 128 + lq;
#pragma unroll
    for (int dblk = 0; dblk < 4; ++dblk)
      mp[dblk * 32] = f2bf(o[dblk][r] * lv);
  }
}

// ------------------------------------------------------------------- launcher
extern "C" void kernel_launch(void* const* d_in, const int* in_sizes, int n_in,
                              void* d_out, int out_size, void* d_ws, size_t ws_size,
                              hipStream_t stream) {
  const float* X  = (const float*)d_in[0];
  const float* Wq = (const float*)d_in[1];
  const float* bq = (const float*)d_in[2];
  const float* Wk = (const float*)d_in[3];
  const float* bk = (const float*)d_in[4];
  const float* Wv = (const float*)d_in[5];
  const float* bv = (const float*)d_in[6];
  const float* Wo = (const float*)d_in[7];
  const float* bo = (const float*)d_in[8];
  float* Out = (float*)d_out;

  char* ws = (char*)d_ws;
  ushort* Xb   = (ushort*)(ws);              // 16 MB  [B*S,2048]
  ushort* Wqb  = (ushort*)(ws + 16777216);   //  8 MB
  ushort* Wkb  = (ushort*)(ws + 25165824);   //  2 MB
  ushort* Wvb  = (ushort*)(ws + 27262976);   //  2 MB
  ushort* Wob  = (ushort*)(ws + 29360128);   //  8 MB
  ushort* Qb   = (ushort*)(ws + 37748736);   // 16 MB  [B*S,2048]
  ushort* Kbuf = (ushort*)(ws + 54525952);   //  4 MB  [B*S,512]
  ushort* Vtb  = (ushort*)(ws + 58720256);   //  4 MB  [B,512,S] (transposed)
  ushort* Midb = (ushort*)(ws + 62914560);   // 16 MB  [B*S,2048]

  auto cast = [&](const float* src, ushort* dst, int n) {
    int n4 = n >> 2;
    int blocks = (n4 + 255) >> 8;
    if (blocks > 2048) blocks = 2048;
    cast_f32_to_bf16<<<dim3(blocks), dim3(256), 0, stream>>>(src, dst, n4);
  };
  cast(X,  Xb,  8388608);
  cast(Wq, Wqb, 4194304);
  cast(Wk, Wkb, 1048576);
  cast(Wv, Wvb, 1048576);
  cast(Wo, Wob, 4194304);

  qkv_gemm<<<dim3(24, 32), 256, 0, stream>>>(Xb, Wqb, Wkb, Wvb, bq, bk, bv,
                                             Qb, Kbuf, Vtb);
  attn_fwd<<<dim3(16, 16, 2), 256, 0, stream>>>(Qb, Kbuf, Vtb, Midb);
  out_gemm<<<dim3(16, 32), 256, 0, stream>>>(Midb, Wob, bo, Out);
}